// Round 2
// baseline (8539.216 us; speedup 1.0000x reference)
//
#include <hip/hip_runtime.h>

// ---------------------------------------------------------------------------
// LayerNorm-LSTM (2 layers) + softmax head.  B=1024 T=100 D=300 U=512 C=14
// Round 2: split-bf16 (hi+lo) GEMM for ~fp32 product accuracy.
//   z = A@B with A,B each split into bf16 hi+lo; 3 MFMAs per fragment pair.
// ---------------------------------------------------------------------------

typedef __bf16 bf16x8 __attribute__((ext_vector_type(8)));
typedef float f32x4 __attribute__((ext_vector_type(4)));
typedef unsigned short u16x8 __attribute__((ext_vector_type(8)));

__device__ __forceinline__ unsigned short f2bf(float f) {
  unsigned int u = __builtin_bit_cast(unsigned int, f);
  u += 0x7fffu + ((u >> 16) & 1u);   // round-to-nearest-even
  return (unsigned short)(u >> 16);
}
__device__ __forceinline__ float bf2f(unsigned short h) {
  unsigned int u = ((unsigned int)h) << 16;
  return __builtin_bit_cast(float, u);
}

// ---------------------------------------------------------------------------
// Weight prep: W [K, N] fp32 row-major -> Bh/Bl [N, Kp] bf16 row-major (split),
// zero-padded for k in [K, Kp).
// ---------------------------------------------------------------------------
__global__ __launch_bounds__(256) void transpose_split(
    const float* __restrict__ W, unsigned short* __restrict__ Bh,
    unsigned short* __restrict__ Bl, int K, int N, int Kp) {
  __shared__ float s[32][33];
  int n0 = blockIdx.x * 32;
  int k0 = blockIdx.y * 32;
  int tid = threadIdx.x;
  int c = tid & 31, r8 = tid >> 5;
  for (int rr = r8; rr < 32; rr += 8) {
    int k = k0 + rr;
    s[rr][c] = (k < K) ? W[(long)k * N + (n0 + c)] : 0.0f;
  }
  __syncthreads();
  for (int rr = r8; rr < 32; rr += 8) {
    int n = n0 + rr;
    float v = s[c][rr];
    unsigned short hi = f2bf(v);
    unsigned short lo = f2bf(v - bf2f(hi));
    Bh[(long)n * Kp + (k0 + c)] = hi;
    Bl[(long)n * Kp + (k0 + c)] = lo;
  }
}

// ---------------------------------------------------------------------------
// Dual GEMM: Z[M=1024, N=2048] = A1[M,K1] @ B1 + A2[M,K2] @ B2
// B pre-transposed split-bf16 [N, Kp] (hi+lo).  A fp32 -> split-bf16 staging.
// Block tile 64x128, BK=32, 256 threads (4 waves), wave tile 64x32.
// Per fragment pair: acc += Al*Bh + Ah*Bl + Ah*Bh   (Al*Bl ~2^-18, dropped)
// ---------------------------------------------------------------------------
#define BM 64
#define BN 128
#define BK 32

__global__ __launch_bounds__(256) void gemm2(
    const float* __restrict__ A1, int lda1, int K1,
    const unsigned short* __restrict__ B1h, const unsigned short* __restrict__ B1l, int K1p,
    const float* __restrict__ A2, int lda2, int K2,
    const unsigned short* __restrict__ B2h, const unsigned short* __restrict__ B2l, int K2p,
    float* __restrict__ Z) {
  __shared__ unsigned short sAh[BM * 40];   // rows padded 32 -> 40 bf16
  __shared__ unsigned short sAl[BM * 40];
  __shared__ unsigned short sBh[BN * 40];
  __shared__ unsigned short sBl[BN * 40];

  int tid = threadIdx.x;
  int bn0 = blockIdx.x * BN;
  int bm0 = blockIdx.y * BM;
  int lane = tid & 63, w = tid >> 6;
  int l15 = lane & 15, quad = lane >> 4;

  f32x4 acc[4][2] = {};

  int rA = tid >> 2, kcA = (tid & 3) * 8;   // A staging: 4 thr/row, 8 f32 each
  int nB = tid >> 1, kcB = (tid & 1) * 16;  // B staging: 2 thr/row, 16 bf16 each

  for (int pass = 0; pass < 2; ++pass) {
    const float* A = pass ? A2 : A1;
    const unsigned short* Bth = pass ? B2h : B1h;
    const unsigned short* Btl = pass ? B2l : B1l;
    int K = pass ? K2 : K1;
    int Kp = pass ? K2p : K1p;
    int lda = pass ? lda2 : lda1;
    const float* Abase = A + (long)(bm0 + rA) * lda;
    const unsigned short* Bbh = Bth + (long)(bn0 + nB) * Kp;
    const unsigned short* Bbl = Btl + (long)(bn0 + nB) * Kp;

    for (int k0 = 0; k0 < Kp; k0 += BK) {
      // ---- stage A tile (64 x 32 fp32 -> split bf16) ----
      float v[8];
      if (k0 + BK <= K) {
        const float4* ap = (const float4*)(Abase + k0 + kcA);
        float4 p0 = ap[0], p1 = ap[1];
        v[0] = p0.x; v[1] = p0.y; v[2] = p0.z; v[3] = p0.w;
        v[4] = p1.x; v[5] = p1.y; v[6] = p1.z; v[7] = p1.w;
      } else {
#pragma unroll
        for (int i = 0; i < 8; ++i) {
          int k = k0 + kcA + i;
          v[i] = (k < K) ? Abase[k] : 0.0f;
        }
      }
      u16x8 uh, ul;
#pragma unroll
      for (int i = 0; i < 8; ++i) {
        unsigned short hi = f2bf(v[i]);
        uh[i] = hi;
        ul[i] = f2bf(v[i] - bf2f(hi));
      }
      *(u16x8*)&sAh[rA * 40 + kcA] = uh;
      *(u16x8*)&sAl[rA * 40 + kcA] = ul;

      // ---- stage B tile (128 x 32 bf16, hi+lo) ----
      const uint4* bph = (const uint4*)(Bbh + k0 + kcB);
      const uint4* bpl = (const uint4*)(Bbl + k0 + kcB);
      uint4 qh0 = bph[0], qh1 = bph[1];
      uint4 ql0 = bpl[0], ql1 = bpl[1];
      *(uint4*)&sBh[nB * 40 + kcB]     = qh0;
      *(uint4*)&sBh[nB * 40 + kcB + 8] = qh1;
      *(uint4*)&sBl[nB * 40 + kcB]     = ql0;
      *(uint4*)&sBl[nB * 40 + kcB + 8] = ql1;

      __syncthreads();

      bf16x8 ah[4], al[4], bh[2], bl[2];
#pragma unroll
      for (int i = 0; i < 4; ++i) {
        ah[i] = __builtin_bit_cast(bf16x8, *(const u16x8*)&sAh[(i * 16 + l15) * 40 + quad * 8]);
        al[i] = __builtin_bit_cast(bf16x8, *(const u16x8*)&sAl[(i * 16 + l15) * 40 + quad * 8]);
      }
#pragma unroll
      for (int j = 0; j < 2; ++j) {
        bh[j] = __builtin_bit_cast(bf16x8, *(const u16x8*)&sBh[(w * 32 + j * 16 + l15) * 40 + quad * 8]);
        bl[j] = __builtin_bit_cast(bf16x8, *(const u16x8*)&sBl[(w * 32 + j * 16 + l15) * 40 + quad * 8]);
      }
#pragma unroll
      for (int i = 0; i < 4; ++i)
#pragma unroll
        for (int j = 0; j < 2; ++j) {
          acc[i][j] = __builtin_amdgcn_mfma_f32_16x16x32_bf16(al[i], bh[j], acc[i][j], 0, 0, 0);
          acc[i][j] = __builtin_amdgcn_mfma_f32_16x16x32_bf16(ah[i], bl[j], acc[i][j], 0, 0, 0);
          acc[i][j] = __builtin_amdgcn_mfma_f32_16x16x32_bf16(ah[i], bh[j], acc[i][j], 0, 0, 0);
        }

      __syncthreads();
    }
  }

  // epilogue: D mapping col=lane&15, row=quad*4+r (m89-verified)
#pragma unroll
  for (int i = 0; i < 4; ++i) {
#pragma unroll
    for (int j = 0; j < 2; ++j) {
      int row = bm0 + i * 16 + quad * 4;
      int col = bn0 + w * 32 + j * 16 + l15;
      float* zp = Z + (long)row * 2048 + col;
#pragma unroll
      for (int r = 0; r < 4; ++r) zp[(long)r * 2048] = acc[i][j][r];
    }
  }
}

// ---------------------------------------------------------------------------
// LayerNorm (per gate over U=512) + bias + gates + cell/hidden update + mask.
// One block per batch row b; wave w handles gate w.
// ---------------------------------------------------------------------------
__global__ __launch_bounds__(256) void ln_gates(
    const float* __restrict__ z, const float* __restrict__ gamma,
    const float* __restrict__ beta, const float* __restrict__ bias,
    const int* __restrict__ mask, int t,
    float* __restrict__ h, float* __restrict__ c) {
  __shared__ float act[2048];
  int b = blockIdx.x;
  int tid = threadIdx.x;
  int w = tid >> 6, lane = tid & 63;

  const float* zb = z + (long)b * 2048 + w * 512;
  float zv[8];
  float sum = 0.0f, sq = 0.0f;
#pragma unroll
  for (int i = 0; i < 8; ++i) {
    float v = zb[lane + 64 * i];
    zv[i] = v;
    sum += v;
    sq += v * v;
  }
#pragma unroll
  for (int off = 32; off; off >>= 1) {
    sum += __shfl_xor(sum, off);
    sq += __shfl_xor(sq, off);
  }
  float mu = sum * (1.0f / 512.0f);
  float var = sq * (1.0f / 512.0f) - mu * mu;
  float is = rsqrtf(var + 1e-3f);

#pragma unroll
  for (int i = 0; i < 8; ++i) {
    int k = lane + 64 * i;
    float val = gamma[w * 512 + k] * (zv[i] - mu) * is + beta[w * 512 + k] + bias[w * 512 + k];
    float a;
    if (w == 2) {
      a = 2.0f / (1.0f + __expf(-2.0f * val)) - 1.0f;  // tanh, saturation-safe
    } else {
      a = 1.0f / (1.0f + __expf(-val));                 // sigmoid
    }
    act[w * 512 + k] = a;
  }
  __syncthreads();

  bool m = mask[(long)b * 100 + t] > 0;
#pragma unroll
  for (int i = 0; i < 2; ++i) {
    int u = tid + 256 * i;
    float co = c[(long)b * 512 + u];
    float ho = h[(long)b * 512 + u];
    float cn = act[512 + u] * co + act[u] * act[1024 + u];
    float th = 2.0f / (1.0f + __expf(-2.0f * cn)) - 1.0f;
    float hn = act[1536 + u] * th;
    h[(long)b * 512 + u] = m ? hn : ho;
    c[(long)b * 512 + u] = m ? cn : co;
  }
}

// ---------------------------------------------------------------------------
// Head: out[b,:] = softmax(h1[b,:] @ Wd + bd),  Wd [512,14]
// ---------------------------------------------------------------------------
__global__ __launch_bounds__(64) void head_kernel(
    const float* __restrict__ h, const float* __restrict__ Wd,
    const float* __restrict__ bd, float* __restrict__ out) {
  __shared__ float hs[512];
  __shared__ float lg[16];
  int b = blockIdx.x, tid = threadIdx.x;
#pragma unroll
  for (int i = 0; i < 8; ++i) hs[tid + 64 * i] = h[(long)b * 512 + tid + 64 * i];
  __syncthreads();
  if (tid < 14) {
    float s = bd[tid];
    for (int k = 0; k < 512; ++k) s += hs[k] * Wd[k * 14 + tid];
    lg[tid] = s;
  }
  __syncthreads();
  if (tid < 14) {
    float mx = lg[0];
#pragma unroll
    for (int i = 1; i < 14; ++i) mx = fmaxf(mx, lg[i]);
    float e = __expf(lg[tid] - mx);
    float den = 0.0f;
#pragma unroll
    for (int i = 0; i < 14; ++i) den += __expf(lg[i] - mx);
    out[(long)b * 14 + tid] = e / den;
  }
}

// ---------------------------------------------------------------------------
extern "C" void kernel_launch(void* const* d_in, const int* in_sizes, int n_in,
                              void* d_out, int out_size, void* d_ws, size_t ws_size,
                              hipStream_t stream) {
  const float* x   = (const float*)d_in[0];
  const int* mask  = (const int*)d_in[1];
  const float* W0  = (const float*)d_in[2];
  const float* U0w = (const float*)d_in[3];
  const float* b0  = (const float*)d_in[4];
  const float* g0  = (const float*)d_in[5];
  const float* be0 = (const float*)d_in[6];
  const float* W1  = (const float*)d_in[7];
  const float* U1w = (const float*)d_in[8];
  const float* b1  = (const float*)d_in[9];
  const float* g1  = (const float*)d_in[10];
  const float* be1 = (const float*)d_in[11];
  const float* Wd  = (const float*)d_in[12];
  const float* bd  = (const float*)d_in[13];
  float* out = (float*)d_out;

  char* p = (char*)d_ws;
  float* h0 = (float*)(p + (size_t)0);
  float* c0 = (float*)(p + ((size_t)2 << 20));
  float* h1 = (float*)(p + ((size_t)4 << 20));
  float* c1 = (float*)(p + ((size_t)6 << 20));
  float* z  = (float*)(p + ((size_t)8 << 20));           // 8 MB
  size_t off = (size_t)16 << 20;
  const size_t szW0 = (size_t)2048 * 320 * 2;   // 1310720
  const size_t szU  = (size_t)2048 * 512 * 2;   // 2097152
  unsigned short* W0h = (unsigned short*)(p + off); off += szW0;
  unsigned short* W0l = (unsigned short*)(p + off); off += szW0;
  unsigned short* U0h = (unsigned short*)(p + off); off += szU;
  unsigned short* U0l = (unsigned short*)(p + off); off += szU;
  unsigned short* W1h = (unsigned short*)(p + off); off += szU;
  unsigned short* W1l = (unsigned short*)(p + off); off += szU;
  unsigned short* U1h = (unsigned short*)(p + off); off += szU;
  unsigned short* U1l = (unsigned short*)(p + off); off += szU;

  // zero h/c states (ws is poisoned 0xAA before every call)
  hipMemsetAsync(p, 0, (size_t)8 << 20, stream);

  // weight prep (every call; no static guards allowed)
  transpose_split<<<dim3(64, 10), 256, 0, stream>>>(W0,  W0h, W0l, 300, 2048, 320);
  transpose_split<<<dim3(64, 16), 256, 0, stream>>>(U0w, U0h, U0l, 512, 2048, 512);
  transpose_split<<<dim3(64, 16), 256, 0, stream>>>(W1,  W1h, W1l, 512, 2048, 512);
  transpose_split<<<dim3(64, 16), 256, 0, stream>>>(U1w, U1h, U1l, 512, 2048, 512);

  for (int t = 0; t < 100; ++t) {
    // layer 0: z = x_t @ W0 + h0 @ U0
    gemm2<<<dim3(16, 16), 256, 0, stream>>>(x + (long)t * 300, 30000, 300, W0h, W0l, 320,
                                            h0, 512, 512, U0h, U0l, 512, z);
    ln_gates<<<1024, 256, 0, stream>>>(z, g0, be0, b0, mask, t, h0, c0);
    // layer 1: z = h0 @ W1 + h1 @ U1
    gemm2<<<dim3(16, 16), 256, 0, stream>>>(h0, 512, 512, W1h, W1l, 512,
                                            h1, 512, 512, U1h, U1l, 512, z);
    ln_gates<<<1024, 256, 0, stream>>>(z, g1, be1, b1, mask, t, h1, c1);
  }

  head_kernel<<<1024, 64, 0, stream>>>(h1, Wd, bd, out);
}

// Round 3
// 7662.267 us; speedup vs baseline: 1.1145x; 1.1145x over previous
//
#include <hip/hip_runtime.h>

// ---------------------------------------------------------------------------
// LayerNorm-LSTM (2 layers) + softmax head.  B=1024 T=100 D=300 U=512 C=14
// Round 3:
//   - fp16 single-MFMA GEMM (was split-bf16 3x MFMA)
//   - hoist x@W0 over all T into one parallel GEMM (ws-guarded, fp16 out)
//   - no-LDS GEMM: direct-global MFMA fragments (operands are L2-resident),
//     no barriers -> compiler software-pipelines loads across k
//   - h states stored fp16 by ln_gates (GEMM A needs no conversion)
// ---------------------------------------------------------------------------

typedef _Float16 f16;
typedef _Float16 f16x8 __attribute__((ext_vector_type(8)));
typedef float f32x4 __attribute__((ext_vector_type(4)));

// ---------------------------------------------------------------------------
// x [rows,300] fp32 (row stride lda) -> xh [rows,320] f16 zero-padded
// ---------------------------------------------------------------------------
__global__ __launch_bounds__(256) void convert_x(
    const float* __restrict__ x, long lda, f16* __restrict__ xh, int rows) {
  int idx = blockIdx.x * 256 + threadIdx.x;
  if (idx >= rows * 320) return;
  int row = idx / 320, k = idx - row * 320;
  xh[idx] = (k < 300) ? (f16)x[(long)row * lda + k] : (f16)0.f;
}

// ---------------------------------------------------------------------------
// W [K,N] fp32 row-major -> Bt [N,Kp] f16 row-major, zero-padded k in [K,Kp)
// ---------------------------------------------------------------------------
__global__ __launch_bounds__(256) void transpose_f16(
    const float* __restrict__ W, f16* __restrict__ Bt, int K, int N, int Kp) {
  __shared__ float s[32][33];
  int n0 = blockIdx.x * 32, k0 = blockIdx.y * 32;
  int tid = threadIdx.x, c = tid & 31, r8 = tid >> 5;
  for (int rr = r8; rr < 32; rr += 8) {
    int k = k0 + rr;
    s[rr][c] = (k < K) ? W[(long)k * N + (n0 + c)] : 0.0f;
  }
  __syncthreads();
  for (int rr = r8; rr < 32; rr += 8)
    Bt[(long)(n0 + rr) * Kp + (k0 + c)] = (f16)s[c][rr];
}

// ---------------------------------------------------------------------------
// GEMM (direct-global fragments, no LDS, no barriers):
//   Z[M, 2048] = (Cin?) + A1[M,K1] @ B1^T + (K2? A2[M,K2] @ B2^T)
// A row-major f16 (row stride lda).  B stored [2048, K] f16 row-major (=B^T).
// Block tile 64x128: 4 waves, wave tile 64x32 (4x2 frags, 16x16x32 f16 MFMA).
// All K multiples of 32.  Out: Zf (fp32) or Zh (f16), ld 2048.
// ---------------------------------------------------------------------------
__global__ __launch_bounds__(256) void gemm_f16(
    const f16* __restrict__ A1, long lda1, int K1, const f16* __restrict__ B1,
    const f16* __restrict__ A2, long lda2, int K2, const f16* __restrict__ B2,
    const f16* __restrict__ Cin, long ldc,
    float* __restrict__ Zf, f16* __restrict__ Zh) {
  int tid = threadIdx.x;
  int lane = tid & 63, w = tid >> 6;
  int l15 = lane & 15, quad = lane >> 4;
  long bn0 = (long)blockIdx.x * 128 + w * 32;
  long bm0 = (long)blockIdx.y * 64;

  f32x4 acc[4][2] = {};

  for (int pass = 0; pass < 2; ++pass) {
    int K = pass ? K2 : K1;
    if (K == 0) continue;
    const f16* A = pass ? A2 : A1;
    const f16* Bt = pass ? B2 : B1;
    long lda = pass ? lda2 : lda1;
    const f16* a0 = A + (bm0 + l15) * lda + quad * 8;
    const f16* b0 = Bt + (bn0 + l15) * (long)K + quad * 8;

    for (int k0 = 0; k0 < K; k0 += 32) {
      f16x8 af[4], bf[2];
#pragma unroll
      for (int i = 0; i < 4; ++i)
        af[i] = *(const f16x8*)(a0 + (long)i * 16 * lda + k0);
#pragma unroll
      for (int j = 0; j < 2; ++j)
        bf[j] = *(const f16x8*)(b0 + (long)j * 16 * K + k0);
#pragma unroll
      for (int i = 0; i < 4; ++i)
#pragma unroll
        for (int j = 0; j < 2; ++j)
          acc[i][j] = __builtin_amdgcn_mfma_f32_16x16x32_f16(af[i], bf[j], acc[i][j], 0, 0, 0);
    }
  }

  // epilogue: D mapping col=lane&15, row=quad*4+r
#pragma unroll
  for (int i = 0; i < 4; ++i) {
    long row = bm0 + i * 16 + quad * 4;
#pragma unroll
    for (int j = 0; j < 2; ++j) {
      long col = bn0 + j * 16 + l15;
#pragma unroll
      for (int r = 0; r < 4; ++r) {
        float v = acc[i][j][r];
        if (Cin) v += (float)Cin[(row + r) * ldc + col];
        if (Zf) Zf[(row + r) * 2048 + col] = v;
        else    Zh[(row + r) * 2048 + col] = (f16)v;
      }
    }
  }
}

// ---------------------------------------------------------------------------
// LayerNorm (per gate over U=512) + bias + gates + cell/hidden update + mask.
// One block per batch row; wave w handles gate w.  h stored f16, c fp32.
// ---------------------------------------------------------------------------
__global__ __launch_bounds__(256) void ln_gates(
    const float* __restrict__ z, const float* __restrict__ gamma,
    const float* __restrict__ beta, const float* __restrict__ bias,
    const int* __restrict__ mask, int t,
    f16* __restrict__ h, float* __restrict__ c) {
  __shared__ float act[2048];
  int b = blockIdx.x;
  int tid = threadIdx.x;
  int w = tid >> 6, lane = tid & 63;

  const float* zb = z + (long)b * 2048 + w * 512;
  float zv[8];
  float sum = 0.0f, sq = 0.0f;
#pragma unroll
  for (int i = 0; i < 8; ++i) {
    float v = zb[lane + 64 * i];
    zv[i] = v;
    sum += v;
    sq += v * v;
  }
#pragma unroll
  for (int off = 32; off; off >>= 1) {
    sum += __shfl_xor(sum, off);
    sq += __shfl_xor(sq, off);
  }
  float mu = sum * (1.0f / 512.0f);
  float var = sq * (1.0f / 512.0f) - mu * mu;
  float is = rsqrtf(var + 1e-3f);

#pragma unroll
  for (int i = 0; i < 8; ++i) {
    int k = lane + 64 * i;
    float val = gamma[w * 512 + k] * (zv[i] - mu) * is + beta[w * 512 + k] + bias[w * 512 + k];
    float a;
    if (w == 2) {
      a = 2.0f / (1.0f + __expf(-2.0f * val)) - 1.0f;  // tanh
    } else {
      a = 1.0f / (1.0f + __expf(-val));                // sigmoid
    }
    act[w * 512 + k] = a;
  }
  __syncthreads();

  bool m = mask[(long)b * 100 + t] > 0;
#pragma unroll
  for (int i = 0; i < 2; ++i) {
    int u = tid + 256 * i;
    float co = c[(long)b * 512 + u];
    float ho = (float)h[(long)b * 512 + u];
    float cn = act[512 + u] * co + act[u] * act[1024 + u];
    float th = 2.0f / (1.0f + __expf(-2.0f * cn)) - 1.0f;
    float hn = act[1536 + u] * th;
    h[(long)b * 512 + u] = (f16)(m ? hn : ho);
    c[(long)b * 512 + u] = m ? cn : co;
  }
}

// ---------------------------------------------------------------------------
// Head: out[b,:] = softmax(h1[b,:] @ Wd + bd),  Wd [512,14],  h1 f16
// ---------------------------------------------------------------------------
__global__ __launch_bounds__(64) void head_kernel(
    const f16* __restrict__ h, const float* __restrict__ Wd,
    const float* __restrict__ bd, float* __restrict__ out) {
  __shared__ float hs[512];
  __shared__ float lg[16];
  int b = blockIdx.x, tid = threadIdx.x;
#pragma unroll
  for (int i = 0; i < 8; ++i) hs[tid + 64 * i] = (float)h[(long)b * 512 + tid + 64 * i];
  __syncthreads();
  if (tid < 14) {
    float s = bd[tid];
    for (int k = 0; k < 512; ++k) s += hs[k] * Wd[k * 14 + tid];
    lg[tid] = s;
  }
  __syncthreads();
  if (tid < 14) {
    float mx = lg[0];
#pragma unroll
    for (int i = 1; i < 14; ++i) mx = fmaxf(mx, lg[i]);
    float e = __expf(lg[tid] - mx);
    float den = 0.0f;
#pragma unroll
    for (int i = 0; i < 14; ++i) den += __expf(lg[i] - mx);
    out[(long)b * 14 + tid] = e / den;
  }
}

// ---------------------------------------------------------------------------
extern "C" void kernel_launch(void* const* d_in, const int* in_sizes, int n_in,
                              void* d_out, int out_size, void* d_ws, size_t ws_size,
                              hipStream_t stream) {
  const float* x   = (const float*)d_in[0];
  const int* mask  = (const int*)d_in[1];
  const float* W0  = (const float*)d_in[2];
  const float* U0w = (const float*)d_in[3];
  const float* b0  = (const float*)d_in[4];
  const float* g0  = (const float*)d_in[5];
  const float* be0 = (const float*)d_in[6];
  const float* W1  = (const float*)d_in[7];
  const float* U1w = (const float*)d_in[8];
  const float* b1  = (const float*)d_in[9];
  const float* g1  = (const float*)d_in[10];
  const float* be1 = (const float*)d_in[11];
  const float* Wd  = (const float*)d_in[12];
  const float* bd  = (const float*)d_in[13];
  float* out = (float*)d_out;

  char* p = (char*)d_ws;
  // layout (bytes)
  f16*   h0  = (f16*)(p + 0);                       // 1 MB
  f16*   h1  = (f16*)(p + ((size_t)1 << 20));       // 1 MB
  float* c0  = (float*)(p + ((size_t)2 << 20));     // 2 MB
  float* c1  = (float*)(p + ((size_t)4 << 20));     // 2 MB
  float* z   = (float*)(p + ((size_t)6 << 20));     // 8 MB  [6,14)
  f16*   W0t = (f16*)(p + ((size_t)14 << 20));                       // 2048*320*2
  f16*   U0t = (f16*)(p + ((size_t)14 << 20) + 1310720);             // 2048*512*2
  f16*   W1t = (f16*)(p + ((size_t)14 << 20) + 1310720 + 2097152);
  f16*   U1t = (f16*)(p + ((size_t)14 << 20) + 1310720 + 2 * 2097152);
  f16*   xh  = (f16*)(p + ((size_t)22 << 20));      // up to 102400*320*2 = 65,536,000
  f16*   z0x = (f16*)(p + ((size_t)96 << 20));      // 102400*2048*2 = 419,430,400

  const size_t need_hoist = ((size_t)96 << 20) + (size_t)102400 * 2048 * 2;
  const size_t need_xh    = ((size_t)22 << 20) + (size_t)102400 * 320 * 2;
  const bool hoist   = ws_size >= need_hoist;
  const bool full_xh = ws_size >= need_xh;

  // zero states (ws is re-poisoned 0xAA before every call)
  hipMemsetAsync(p, 0, (size_t)6 << 20, stream);

  // weight prep
  transpose_f16<<<dim3(64, 10), 256, 0, stream>>>(W0,  W0t, 300, 2048, 320);
  transpose_f16<<<dim3(64, 16), 256, 0, stream>>>(U0w, U0t, 512, 2048, 512);
  transpose_f16<<<dim3(64, 16), 256, 0, stream>>>(W1,  W1t, 512, 2048, 512);
  transpose_f16<<<dim3(64, 16), 256, 0, stream>>>(U1w, U1t, 512, 2048, 512);

  if (full_xh) {
    // x -> f16, padded rows [102400, 320]
    convert_x<<<(102400 * 320 + 255) / 256, 256, 0, stream>>>(x, 300, xh, 102400);
  }
  if (hoist) {
    // z0x[b*100+t, :] = x[b,t,:] @ W0   (one big parallel GEMM, f16 out)
    gemm_f16<<<dim3(16, 1600), 256, 0, stream>>>(
        xh, 320, 320, W0t, nullptr, 0, 0, nullptr, nullptr, 0, nullptr, z0x);
  }

  for (int t = 0; t < 100; ++t) {
    if (hoist) {
      // layer 0: z = z0x[:,t] + h0 @ U0
      gemm_f16<<<dim3(16, 16), 256, 0, stream>>>(
          h0, 512, 512, U0t, nullptr, 0, 0, nullptr,
          z0x + (long)t * 2048, 204800, z, nullptr);
    } else if (full_xh) {
      gemm_f16<<<dim3(16, 16), 256, 0, stream>>>(
          xh + (long)t * 320, 32000, 320, W0t, h0, 512, 512, U0t,
          nullptr, 0, z, nullptr);
    } else {
      // convert just this timestep's x slice into xh[0..1024)
      convert_x<<<(1024 * 320 + 255) / 256, 256, 0, stream>>>(x + (long)t * 300, 30000, xh, 1024);
      gemm_f16<<<dim3(16, 16), 256, 0, stream>>>(
          xh, 320, 320, W0t, h0, 512, 512, U0t, nullptr, 0, z, nullptr);
    }
    ln_gates<<<1024, 256, 0, stream>>>(z, g0, be0, b0, mask, t, h0, c0);

    // layer 1: z = h0 @ W1 + h1 @ U1
    gemm_f16<<<dim3(16, 16), 256, 0, stream>>>(
        h0, 512, 512, W1t, h1, 512, 512, U1t, nullptr, 0, z, nullptr);
    ln_gates<<<1024, 256, 0, stream>>>(z, g1, be1, b1, mask, t, h1, c1);
  }

  head_kernel<<<1024, 64, 0, stream>>>(h1, Wd, bd, out);
}